// Round 5
// baseline (238.612 us; speedup 1.0000x reference)
//
#include <hip/hip_runtime.h>

// MaskPatchClassificationHead — B=4, P=256, F=512
// Single fused kernel, 256 blocks x 512 threads (1 block/CU, all co-resident):
//   phase 1: fc partial GEMM (K-split 2) + label sigs
//   phase 2: score partial GEMM (h h^T, K-split 4)
//   phase 3: softmax/KL loss + atomicAdd; block 0 gathers + writes out
// Two-hop grid barrier: arrive(per-block magic slot) -> block-0 gather ->
// single release word broadcast. Exact-match magics => robust to 0xAA poison;
// agent-scope atomics for cross-XCD visibility; bounded spins (no hangs).

#define INV_TAU (1.0f / 0.07f)
#define EPSC 1e-5f

constexpr int Bz = 4;
constexpr int Pn = 256;
constexpr int Fdim = 512;
constexpr int Mrows = Bz * Pn;                       // 1024
constexpr size_t HP_STRIDE = (size_t)Mrows * Fdim;   // per fc K-half partial
constexpr size_t SP_STRIDE = (size_t)Bz * Pn * Pn;   // per score K-quarter partial
constexpr int LS = 65;                               // LDS tile stride (writes 2-way = free)

__device__ __forceinline__ float wave_sum(float v) {
  #pragma unroll
  for (int o = 32; o > 0; o >>= 1) v += __shfl_down(v, o, 64);
  return v;
}
__device__ __forceinline__ float wave_max(float v) {
  #pragma unroll
  for (int o = 32; o > 0; o >>= 1) v = fmaxf(v, __shfl_down(v, o, 64));
  return v;
}
__device__ __forceinline__ unsigned long long mix64(unsigned long long z) {
  z ^= z >> 33; z *= 0xff51afd7ed558ccdULL;
  z ^= z >> 33; z *= 0xc4ceb9fe1a85ec53ULL;
  z ^= z >> 33; return z;
}

// Two-hop grid barrier. slots: 256 ints; release: 1 int (own cache line).
__device__ __forceinline__ void grid_barrier(int* slots, int* release, int magic) {
  __syncthreads();
  if (threadIdx.x == 0)
    __hip_atomic_store(slots + blockIdx.x, magic, __ATOMIC_RELEASE,
                       __HIP_MEMORY_SCOPE_AGENT);
  if (blockIdx.x == 0) {
    if (threadIdx.x < 256) {
      int spins = 0;
      while (__hip_atomic_load(slots + threadIdx.x, __ATOMIC_ACQUIRE,
                               __HIP_MEMORY_SCOPE_AGENT) != magic) {
        if (++spins > (1 << 20)) break;  // escape: wrong answer, not hang
        __builtin_amdgcn_s_sleep(1);
      }
    }
    __syncthreads();
    if (threadIdx.x == 0)
      __hip_atomic_store(release, magic, __ATOMIC_RELEASE,
                         __HIP_MEMORY_SCOPE_AGENT);
  } else {
    if (threadIdx.x == 0) {
      int spins = 0;
      while (__hip_atomic_load(release, __ATOMIC_ACQUIRE,
                               __HIP_MEMORY_SCOPE_AGENT) != magic) {
        if (++spins > (1 << 20)) break;
        __builtin_amdgcn_s_sleep(1);
      }
    }
  }
  __syncthreads();
}

__global__ __launch_bounds__(512) void fused_kernel(
    const float* __restrict__ A, const float* __restrict__ W,
    const float* __restrict__ labels, const float* __restrict__ bias,
    float* __restrict__ hp, float* __restrict__ Sp,
    ulonglong2* __restrict__ sig, float* __restrict__ acc,
    int* __restrict__ flags, float* __restrict__ out) {
  const int t = threadIdx.x;
  const int bid = blockIdx.x;
  __shared__ float ldsbuf[2 * 32 * LS];
  float (*Ash)[LS] = (float(*)[LS])ldsbuf;
  float (*Bsh)[LS] = (float(*)[LS])(ldsbuf + 32 * LS);

  int* slots1 = flags;          // [0,256)
  int* slots2 = flags + 256;    // [256,512)
  int* slots3 = flags + 512;    // [512,768)
  int* rel1   = flags + 800;    // own line
  int* rel2   = flags + 832;    // own line

  if (bid == 0 && t == 0)
    __hip_atomic_store(acc, 0.0f, __ATOMIC_RELAXED, __HIP_MEMORY_SCOPE_AGENT);

  // ===== phase 1a: label signatures (4 rows/block, one 64-lane group each)
  {
    const int g = t >> 6, lane = t & 63;
    if (g < 4) {
      const int row = bid * 4 + g;
      const uint4* l4 = (const uint4*)(labels + (size_t)row * Fdim);
      unsigned long long h1 = 0, h2 = 0;
      #pragma unroll
      for (int c = lane; c < Fdim / 4; c += 64) {
        uint4 w = l4[c];
        unsigned long long w01 = ((unsigned long long)w.y << 32) | w.x;
        unsigned long long w23 = ((unsigned long long)w.w << 32) | w.z;
        unsigned long long idx = (unsigned long long)c;
        h1 ^= mix64(w01 + idx * 0x9E3779B97F4A7C15ULL + 0x0123456789ABCDEFULL);
        h1 ^= mix64(w23 + idx * 0xC2B2AE3D27D4EB4FULL + 1ULL);
        h2 ^= mix64(w01 ^ (idx * 0x165667B19E3779F9ULL + 7ULL));
        h2 ^= mix64(w23 ^ (idx * 0x27D4EB2F165667C5ULL + 13ULL));
      }
      #pragma unroll
      for (int o = 32; o > 0; o >>= 1) {
        h1 ^= __shfl_down(h1, o, 64);
        h2 ^= __shfl_down(h2, o, 64);
      }
      if (lane == 0) { sig[row].x = h1; sig[row].y = h2; }
    }
  }

  // ===== phase 1b: fc partial GEMM. 64x64 tile, 2x4 micro, BK=32.
  // hp[z][m][n] = sum_{k in half z} A[m][k] W[n][k]
  {
    const int bx = bid & 15, by = (bid >> 4) & 7, bz = bid >> 7;
    const int m0 = bx * 64, n0 = by * 64;
    const int kbase = bz * 256;
    float* C = hp + (size_t)bz * HP_STRIDE;
    const int tx = t & 15, ty = t >> 4;
    const int r0 = t >> 3, c0 = (t & 7) << 2;
    float a2[2][4] = {};

    for (int kc = 0; kc < 256; kc += 32) {
      const float* Ap = A + (size_t)(m0 + r0) * Fdim + kbase + kc + c0;
      const float* Wp = W + (size_t)(n0 + r0) * Fdim + kbase + kc + c0;
      float4 av = *(const float4*)Ap;
      float4 bv = *(const float4*)Wp;
      __syncthreads();
      Ash[c0+0][r0] = av.x; Ash[c0+1][r0] = av.y; Ash[c0+2][r0] = av.z; Ash[c0+3][r0] = av.w;
      Bsh[c0+0][r0] = bv.x; Bsh[c0+1][r0] = bv.y; Bsh[c0+2][r0] = bv.z; Bsh[c0+3][r0] = bv.w;
      __syncthreads();
      #pragma unroll 8
      for (int k = 0; k < 32; ++k) {
        float2 aa = *(const float2*)&Ash[k][ty << 1];
        float4 bb = *(const float4*)&Bsh[k][tx << 2];
        a2[0][0] = fmaf(aa.x, bb.x, a2[0][0]); a2[0][1] = fmaf(aa.x, bb.y, a2[0][1]);
        a2[0][2] = fmaf(aa.x, bb.z, a2[0][2]); a2[0][3] = fmaf(aa.x, bb.w, a2[0][3]);
        a2[1][0] = fmaf(aa.y, bb.x, a2[1][0]); a2[1][1] = fmaf(aa.y, bb.y, a2[1][1]);
        a2[1][2] = fmaf(aa.y, bb.z, a2[1][2]); a2[1][3] = fmaf(aa.y, bb.w, a2[1][3]);
      }
    }
    #pragma unroll
    for (int i = 0; i < 2; ++i) {
      float4 o; o.x = a2[i][0]; o.y = a2[i][1]; o.z = a2[i][2]; o.w = a2[i][3];
      *(float4*)(C + (size_t)(m0 + (ty << 1) + i) * Fdim + n0 + (tx << 2)) = o;
    }
  }

  grid_barrier(slots1, rel1, 0x5EC7A5E1);

  // ===== phase 2: score partial GEMM. Sp[kz][b][p][q], K-quarter kz of
  // h[b*256+m][o] = hp0 + hp1 + bias[o]. 64x64 tile, 2x4 micro.
  {
    const int x = bid & 3, y = (bid >> 2) & 3, z = bid >> 4;
    const int b = z >> 2, kz = z & 3;
    const int kbase = kz * 128;
    const int m0 = x * 64, n0 = y * 64;
    const float* h0 = hp;
    const float* h1 = hp + HP_STRIDE;
    float* C = Sp + (size_t)kz * SP_STRIDE + (size_t)b * Pn * Pn;
    const size_t rb = (size_t)b * Pn;
    const int tx = t & 15, ty = t >> 4;
    const int r0 = t >> 3, c0 = (t & 7) << 2;
    float a2[2][4] = {};

    for (int kc = 0; kc < 128; kc += 32) {
      const int ko = kbase + kc + c0;
      float4 bi = *(const float4*)(bias + ko);
      size_t aoff = (rb + m0 + r0) * Fdim + ko;
      size_t boff = (rb + n0 + r0) * Fdim + ko;
      float4 al = *(const float4*)(h0 + aoff);
      float4 ah = *(const float4*)(h1 + aoff);
      float4 bl = *(const float4*)(h0 + boff);
      float4 bh = *(const float4*)(h1 + boff);
      float4 av, bv;
      av.x = al.x + ah.x + bi.x; av.y = al.y + ah.y + bi.y;
      av.z = al.z + ah.z + bi.z; av.w = al.w + ah.w + bi.w;
      bv.x = bl.x + bh.x + bi.x; bv.y = bl.y + bh.y + bi.y;
      bv.z = bl.z + bh.z + bi.z; bv.w = bl.w + bh.w + bi.w;
      __syncthreads();
      Ash[c0+0][r0] = av.x; Ash[c0+1][r0] = av.y; Ash[c0+2][r0] = av.z; Ash[c0+3][r0] = av.w;
      Bsh[c0+0][r0] = bv.x; Bsh[c0+1][r0] = bv.y; Bsh[c0+2][r0] = bv.z; Bsh[c0+3][r0] = bv.w;
      __syncthreads();
      #pragma unroll 8
      for (int k = 0; k < 32; ++k) {
        float2 aa = *(const float2*)&Ash[k][ty << 1];
        float4 bb = *(const float4*)&Bsh[k][tx << 2];
        a2[0][0] = fmaf(aa.x, bb.x, a2[0][0]); a2[0][1] = fmaf(aa.x, bb.y, a2[0][1]);
        a2[0][2] = fmaf(aa.x, bb.z, a2[0][2]); a2[0][3] = fmaf(aa.x, bb.w, a2[0][3]);
        a2[1][0] = fmaf(aa.y, bb.x, a2[1][0]); a2[1][1] = fmaf(aa.y, bb.y, a2[1][1]);
        a2[1][2] = fmaf(aa.y, bb.z, a2[1][2]); a2[1][3] = fmaf(aa.y, bb.w, a2[1][3]);
      }
    }
    #pragma unroll
    for (int i = 0; i < 2; ++i) {
      float4 o; o.x = a2[i][0]; o.y = a2[i][1]; o.z = a2[i][2]; o.w = a2[i][3];
      *(float4*)(C + (size_t)(m0 + (ty << 1) + i) * Pn + n0 + (tx << 2)) = o;
    }
  }

  grid_barrier(slots2, rel2, 0x5EC7A5E2);

  // ===== phase 3: loss. Block = (b, 4 rows); threads 0..255 active (q).
  {
    const int b = bid >> 6, p0 = (bid & 63) * 4;
    const int q = t;
    const bool act = (t < 256);
    float* invn = ldsbuf;        // 256 floats (reuse of tile LDS)
    float* red  = ldsbuf + 256;  // 12 floats
    const float* S0 = Sp + (size_t)b * Pn * Pn;
    const float* S1 = S0 + SP_STRIDE;
    const float* S2 = S0 + 2 * SP_STRIDE;
    const float* S3 = S0 + 3 * SP_STRIDE;

    ulonglong2 sq; sq.x = 0; sq.y = 0;
    if (act) {
      const int d = q * 257;
      float Sqq = S0[d] + S1[d] + S2[d] + S3[d];
      invn[q] = 1.0f / fmaxf(sqrtf(Sqq), 1e-12f);
      sq = sig[(b << 8) + q];
    }
    __syncthreads();

    float lane_contrib = 0.0f;
    #pragma unroll
    for (int i = 0; i < 4; ++i) {
      const int p = p0 + i;
      float s = -1e30f;
      bool eq = false;
      if (act) {
        const int ro = p << 8;
        float Spq = S0[ro + q] + S1[ro + q] + S2[ro + q] + S3[ro + q];
        s = Spq * invn[p] * invn[q] * INV_TAU;
        ulonglong2 sp = sig[(b << 8) + p];
        if (q == p) eq = true;
        else if (sp.x == sq.x && sp.y == sq.y) {
          bool v = true;
          const float* lp = labels + (size_t)((b << 8) + p) * Fdim;
          const float* lq = labels + (size_t)((b << 8) + q) * Fdim;
          for (int j = 0; j < Fdim; ++j) v = v && (lp[j] == lq[j]);
          eq = v;
        }
      }
      float m = wave_max(s);
      if (act && (q & 63) == 0) red[q >> 6] = m;
      __syncthreads();
      m = fmaxf(fmaxf(red[0], red[1]), fmaxf(red[2], red[3]));

      float e = act ? expf(s - m) : 0.0f;
      float zc = wave_sum(e);
      float cc = wave_sum(eq ? 1.0f : 0.0f);
      if (act && (q & 63) == 0) { red[4 + (q >> 6)] = zc; red[8 + (q >> 6)] = cc; }
      __syncthreads();
      float z = red[4] + red[5] + red[6] + red[7];
      float n = red[8] + red[9] + red[10] + red[11];

      if (act) {
        float prob = fminf(fmaxf(e / z, EPSC), 1.0f - EPSC);
        if (eq) lane_contrib += (-logf(n) - logf(prob)) / n;
      }
      __syncthreads();
    }

    float c = wave_sum(lane_contrib);
    if (act && (t & 63) == 0) red[t >> 6] = c;
    __syncthreads();
    if (t == 0) atomicAdd(acc, red[0] + red[1] + red[2] + red[3]);
  }

  // ===== finalize: gather-only (no broadcast needed)
  __syncthreads();
  if (t == 0)
    __hip_atomic_store(slots3 + bid, 0x5EC7A5E3, __ATOMIC_RELEASE,
                       __HIP_MEMORY_SCOPE_AGENT);
  if (bid == 0) {
    if (t < 256) {
      int spins = 0;
      while (__hip_atomic_load(slots3 + t, __ATOMIC_ACQUIRE,
                               __HIP_MEMORY_SCOPE_AGENT) != 0x5EC7A5E3) {
        if (++spins > (1 << 20)) break;
        __builtin_amdgcn_s_sleep(1);
      }
    }
    __syncthreads();
    if (t == 0)
      out[0] = __hip_atomic_load(acc, __ATOMIC_RELAXED, __HIP_MEMORY_SCOPE_AGENT)
               * (1.0f / (float)(Bz * Pn));
  }
}

extern "C" void kernel_launch(void* const* d_in, const int* in_sizes, int n_in,
                              void* d_out, int out_size, void* d_ws, size_t ws_size,
                              hipStream_t stream) {
  const float* inputs = (const float*)d_in[0];
  const float* labels = (const float*)d_in[1];
  const float* W      = (const float*)d_in[2];
  const float* bias   = (const float*)d_in[3];
  float* out = (float*)d_out;

  char* ws = (char*)d_ws;
  int*   flags = (int*)ws;                         // 3x256 slots + release words
  float* acc   = (float*)(ws + 4096);              // 4 B
  float* hp    = (float*)(ws + 8192);              // 2 * 2 MB fc partials
  float* Sp    = (float*)(ws + 8192 + 2 * HP_STRIDE * 4);  // 4 * 1 MB score partials
  ulonglong2* sig = (ulonglong2*)(ws + 8192 + 2 * HP_STRIDE * 4 + 4 * SP_STRIDE * 4);

  fused_kernel<<<256, 512, 0, stream>>>(inputs, W, labels, bias,
                                        hp, Sp, sig, acc, flags, out);
}

// Round 6
// 134.907 us; speedup vs baseline: 1.7687x; 1.7687x over previous
//
#include <hip/hip_runtime.h>

// MaskPatchClassificationHead — B=4, P=256, F=512
// 2-node graph (no grid barriers — measured: memory-polled barriers cost far
// more than the ~7us/node dispatch overhead they save on MI355X):
//   node A: fc_sig    — fc partial GEMM (K-split 2) + label sigs + acc/done init
//   node B: score_loss — per (batch, 4 p-rows): stream h_q rows, dots + norms
//                        in registers, softmax/KL, atomicAdd, done-count finalize

#define INV_TAU (1.0f / 0.07f)
#define EPSC 1e-5f

constexpr int Bz = 4;
constexpr int Pn = 256;
constexpr int Fdim = 512;
constexpr int Mrows = Bz * Pn;                       // 1024
constexpr size_t HP_STRIDE = (size_t)Mrows * Fdim;   // per fc K-half partial

__device__ __forceinline__ float wave_sum(float v) {
  #pragma unroll
  for (int o = 32; o > 0; o >>= 1) v += __shfl_down(v, o, 64);
  return v;
}
__device__ __forceinline__ float wave_max(float v) {
  #pragma unroll
  for (int o = 32; o > 0; o >>= 1) v = fmaxf(v, __shfl_down(v, o, 64));
  return v;
}
__device__ __forceinline__ unsigned long long mix64(unsigned long long z) {
  z ^= z >> 33; z *= 0xff51afd7ed558ccdULL;
  z ^= z >> 33; z *= 0xc4ceb9fe1a85ec53ULL;
  z ^= z >> 33; return z;
}

// ---------------- node A: fc partial GEMM + label sigs + init
// hp[z][m][n] = sum_{k in half z} A[m][k] W[n][k]
// 64x64 tile, 4x4 micro, BK=32, 256 threads. grid (16,8,2) = 256 blocks.
__global__ __launch_bounds__(256) void fc_sig(const float* __restrict__ A,
                                              const float* __restrict__ W,
                                              const float* __restrict__ labels,
                                              float* __restrict__ hp,
                                              ulonglong2* __restrict__ sig,
                                              float* __restrict__ acc,
                                              unsigned int* __restrict__ done) {
  const int t = threadIdx.x;
  const int bid = blockIdx.x + 16 * (blockIdx.y + 8 * blockIdx.z);
  if (bid == 0 && t == 0) { acc[0] = 0.0f; done[0] = 0u; }

  // --- label signatures: 4 rows/block, one 64-lane group per row
  {
    const int g = t >> 6, lane = t & 63;
    const int row = bid * 4 + g;
    const uint4* l4 = (const uint4*)(labels + (size_t)row * Fdim);
    unsigned long long h1 = 0, h2 = 0;
    #pragma unroll
    for (int c = lane; c < Fdim / 4; c += 64) {
      uint4 w = l4[c];
      unsigned long long w01 = ((unsigned long long)w.y << 32) | w.x;
      unsigned long long w23 = ((unsigned long long)w.w << 32) | w.z;
      unsigned long long idx = (unsigned long long)c;
      h1 ^= mix64(w01 + idx * 0x9E3779B97F4A7C15ULL + 0x0123456789ABCDEFULL);
      h1 ^= mix64(w23 + idx * 0xC2B2AE3D27D4EB4FULL + 1ULL);
      h2 ^= mix64(w01 ^ (idx * 0x165667B19E3779F9ULL + 7ULL));
      h2 ^= mix64(w23 ^ (idx * 0x27D4EB2F165667C5ULL + 13ULL));
    }
    #pragma unroll
    for (int o = 32; o > 0; o >>= 1) {
      h1 ^= __shfl_down(h1, o, 64);
      h2 ^= __shfl_down(h2, o, 64);
    }
    if (lane == 0) { sig[row].x = h1; sig[row].y = h2; }
  }

  // --- fc GEMM (round-2 proven body)
  const int m0 = blockIdx.x * 64, n0 = blockIdx.y * 64;
  const int kbase = blockIdx.z * 256;
  float* C = hp + (size_t)blockIdx.z * HP_STRIDE;
  __shared__ float Ash[32][68];  // [k][m] transposed; b128 reads 16B-aligned
  __shared__ float Bsh[32][68];  // [k][n]
  const int tx = t & 15, ty = t >> 4;
  const int r0 = t >> 3, c0 = (t & 7) << 2;
  float a4[4][4] = {};

  for (int kc = 0; kc < 256; kc += 32) {
    const float* Ap = A + (size_t)(m0 + r0) * Fdim + kbase + kc + c0;
    const float* Wp = W + (size_t)(n0 + r0) * Fdim + kbase + kc + c0;
    float4 a0 = *(const float4*)Ap;
    float4 a1 = *(const float4*)(Ap + 32 * Fdim);
    float4 b0 = *(const float4*)Wp;
    float4 b1 = *(const float4*)(Wp + 32 * Fdim);
    __syncthreads();
    Ash[c0+0][r0] = a0.x; Ash[c0+1][r0] = a0.y; Ash[c0+2][r0] = a0.z; Ash[c0+3][r0] = a0.w;
    Ash[c0+0][r0+32] = a1.x; Ash[c0+1][r0+32] = a1.y; Ash[c0+2][r0+32] = a1.z; Ash[c0+3][r0+32] = a1.w;
    Bsh[c0+0][r0] = b0.x; Bsh[c0+1][r0] = b0.y; Bsh[c0+2][r0] = b0.z; Bsh[c0+3][r0] = b0.w;
    Bsh[c0+0][r0+32] = b1.x; Bsh[c0+1][r0+32] = b1.y; Bsh[c0+2][r0+32] = b1.z; Bsh[c0+3][r0+32] = b1.w;
    __syncthreads();
    #pragma unroll 8
    for (int k = 0; k < 32; ++k) {
      float4 av = *(const float4*)&Ash[k][ty << 2];
      float4 bv = *(const float4*)&Bsh[k][tx << 2];
      a4[0][0] = fmaf(av.x, bv.x, a4[0][0]); a4[0][1] = fmaf(av.x, bv.y, a4[0][1]);
      a4[0][2] = fmaf(av.x, bv.z, a4[0][2]); a4[0][3] = fmaf(av.x, bv.w, a4[0][3]);
      a4[1][0] = fmaf(av.y, bv.x, a4[1][0]); a4[1][1] = fmaf(av.y, bv.y, a4[1][1]);
      a4[1][2] = fmaf(av.y, bv.z, a4[1][2]); a4[1][3] = fmaf(av.y, bv.w, a4[1][3]);
      a4[2][0] = fmaf(av.z, bv.x, a4[2][0]); a4[2][1] = fmaf(av.z, bv.y, a4[2][1]);
      a4[2][2] = fmaf(av.z, bv.z, a4[2][2]); a4[2][3] = fmaf(av.z, bv.w, a4[2][3]);
      a4[3][0] = fmaf(av.w, bv.x, a4[3][0]); a4[3][1] = fmaf(av.w, bv.y, a4[3][1]);
      a4[3][2] = fmaf(av.w, bv.z, a4[3][2]); a4[3][3] = fmaf(av.w, bv.w, a4[3][3]);
    }
  }
  #pragma unroll
  for (int i = 0; i < 4; ++i) {
    float4 o; o.x = a4[i][0]; o.y = a4[i][1]; o.z = a4[i][2]; o.w = a4[i][3];
    *(float4*)(C + (size_t)(m0 + (ty << 2) + i) * Fdim + n0 + (tx << 2)) = o;
  }
}

// ---------------- node B: fused scores + loss.
// grid 256 = (b = bid>>6, p0 = (bid&63)*4), 256 threads (4 waves).
// h_p rows live in registers per lane (cols c0..c0+7); wave w streams q-rows
// w*64..w*64+63 computing 4 dots + norm^2 per row; then softmax/KL per p-row.
__global__ __launch_bounds__(256) void score_loss(const float* __restrict__ hp,
                                                  const float* __restrict__ bias,
                                                  const ulonglong2* __restrict__ sig,
                                                  const float* __restrict__ labels,
                                                  float* __restrict__ acc,
                                                  unsigned int* __restrict__ done,
                                                  float* __restrict__ out) {
  const int bid = blockIdx.x;
  const int b = bid >> 6, p0 = (bid & 63) * 4;
  const int t = threadIdx.x;
  const int w = t >> 6, lane = t & 63;
  const int c0 = lane << 3;  // 8 cols per lane

  __shared__ float dots[4][256];
  __shared__ float invn[256];   // nrm2 then inverted in place
  __shared__ float red[12];

  const float* h0 = hp;
  const float* h1 = hp + HP_STRIDE;
  const float4 bi0 = *(const float4*)(bias + c0);
  const float4 bi1 = *(const float4*)(bias + c0 + 4);

  // h_p rows (4) into registers
  float hpr[4][8];
  #pragma unroll
  for (int g = 0; g < 4; ++g) {
    const size_t off = (size_t)((b << 8) + p0 + g) * Fdim + c0;
    float4 x0 = *(const float4*)(h0 + off);
    float4 x1 = *(const float4*)(h0 + off + 4);
    float4 y0 = *(const float4*)(h1 + off);
    float4 y1 = *(const float4*)(h1 + off + 4);
    hpr[g][0] = x0.x + y0.x + bi0.x; hpr[g][1] = x0.y + y0.y + bi0.y;
    hpr[g][2] = x0.z + y0.z + bi0.z; hpr[g][3] = x0.w + y0.w + bi0.w;
    hpr[g][4] = x1.x + y1.x + bi1.x; hpr[g][5] = x1.y + y1.y + bi1.y;
    hpr[g][6] = x1.z + y1.z + bi1.z; hpr[g][7] = x1.w + y1.w + bi1.w;
  }

  // stream q rows: wave w handles q = w*64 .. w*64+63
  for (int i = 0; i < 64; ++i) {
    const int q = (w << 6) + i;
    const size_t off = (size_t)((b << 8) + q) * Fdim + c0;
    float4 x0 = *(const float4*)(h0 + off);
    float4 x1 = *(const float4*)(h0 + off + 4);
    float4 y0 = *(const float4*)(h1 + off);
    float4 y1 = *(const float4*)(h1 + off + 4);
    float e[8];
    e[0] = x0.x + y0.x + bi0.x; e[1] = x0.y + y0.y + bi0.y;
    e[2] = x0.z + y0.z + bi0.z; e[3] = x0.w + y0.w + bi0.w;
    e[4] = x1.x + y1.x + bi1.x; e[5] = x1.y + y1.y + bi1.y;
    e[6] = x1.z + y1.z + bi1.z; e[7] = x1.w + y1.w + bi1.w;

    float n2 = 0.f, d0 = 0.f, d1 = 0.f, d2 = 0.f, d3 = 0.f;
    #pragma unroll
    for (int j = 0; j < 8; ++j) {
      n2 = fmaf(e[j], e[j], n2);
      d0 = fmaf(e[j], hpr[0][j], d0);
      d1 = fmaf(e[j], hpr[1][j], d1);
      d2 = fmaf(e[j], hpr[2][j], d2);
      d3 = fmaf(e[j], hpr[3][j], d3);
    }
    n2 = wave_sum(n2);
    d0 = wave_sum(d0); d1 = wave_sum(d1);
    d2 = wave_sum(d2); d3 = wave_sum(d3);
    if (lane == 0) {
      invn[q] = n2;
      dots[0][q] = d0; dots[1][q] = d1; dots[2][q] = d2; dots[3][q] = d3;
    }
  }
  __syncthreads();

  // invert norms in place (each thread owns slot t)
  {
    float n2 = invn[t];
    invn[t] = 1.0f / fmaxf(sqrtf(n2), 1e-12f);
  }
  const ulonglong2 sq = sig[(b << 8) + t];
  __syncthreads();

  // loss over the block's 4 p-rows; thread t = q
  const int q = t;
  float lane_contrib = 0.0f;
  #pragma unroll
  for (int g = 0; g < 4; ++g) {
    const int p = p0 + g;
    float s = dots[g][q] * invn[p] * invn[q] * INV_TAU;

    // exact row equality <=> L1 dist == 0. sig mismatch => unequal;
    // sig match with q!=p => exact verify (cold path).
    ulonglong2 sp = sig[(b << 8) + p];
    bool eq;
    if (q == p) eq = true;
    else if (sp.x == sq.x && sp.y == sq.y) {
      bool v = true;
      const float* lp = labels + (size_t)((b << 8) + p) * Fdim;
      const float* lq = labels + (size_t)((b << 8) + q) * Fdim;
      for (int j = 0; j < Fdim; ++j) v = v && (lp[j] == lq[j]);
      eq = v;
    } else eq = false;

    float m = wave_max(s);
    if ((q & 63) == 0) red[q >> 6] = m;
    __syncthreads();
    m = fmaxf(fmaxf(red[0], red[1]), fmaxf(red[2], red[3]));

    float e = expf(s - m);
    float zc = wave_sum(e);
    float cc = wave_sum(eq ? 1.0f : 0.0f);
    if ((q & 63) == 0) { red[4 + (q >> 6)] = zc; red[8 + (q >> 6)] = cc; }
    __syncthreads();
    float z = red[4] + red[5] + red[6] + red[7];
    float n = red[8] + red[9] + red[10] + red[11];

    float prob = fminf(fmaxf(e / z, EPSC), 1.0f - EPSC);
    if (eq) lane_contrib += (-logf(n) - logf(prob)) / n;
    __syncthreads();  // red reused next iteration
  }

  float c = wave_sum(lane_contrib);
  if ((t & 63) == 0) red[t >> 6] = c;
  __syncthreads();
  if (t == 0) {
    atomicAdd(acc, red[0] + red[1] + red[2] + red[3]);
    __threadfence();
    unsigned int v = atomicAdd(done, 1u);
    if (v == 255u) {  // last of 256 blocks: all acc adds visible
      float tot = atomicAdd(acc, 0.0f);
      out[0] = tot * (1.0f / (float)(Bz * Pn));
    }
  }
}

extern "C" void kernel_launch(void* const* d_in, const int* in_sizes, int n_in,
                              void* d_out, int out_size, void* d_ws, size_t ws_size,
                              hipStream_t stream) {
  const float* inputs = (const float*)d_in[0];
  const float* labels = (const float*)d_in[1];
  const float* W      = (const float*)d_in[2];
  const float* bias   = (const float*)d_in[3];
  float* out = (float*)d_out;

  char* ws = (char*)d_ws;
  float* acc         = (float*)ws;                       // 4 B (init by node A)
  unsigned int* done = (unsigned int*)(ws + 4);          // 4 B (init by node A)
  float* hp = (float*)(ws + 256);                        // 2 * 2 MB fc partials
  ulonglong2* sig = (ulonglong2*)(ws + 256 + 2 * HP_STRIDE * 4);  // 16 KB

  fc_sig<<<dim3(16, 8, 2), 256, 0, stream>>>(inputs, W, labels, hp, sig, acc, done);
  score_loss<<<256, 256, 0, stream>>>(hp, bias, sig, labels, acc, done, out);
}